// Round 7
// baseline (9306.749 us; speedup 1.0000x reference)
//
#include <hip/hip_runtime.h>

constexpr int SEQ  = 4096;   // timesteps
constexpr int IN   = 512;    // input size
constexpr int RS   = 2048;   // reservoir size
constexpr int GB   = 64;     // blocks in scan kernel
constexpr int BT   = 1024;   // threads per block in scan kernel
constexpr int RING = 8;      // ring depth (epochs); skew bound <= 1
constexpr float INV_SQRT = 0.022097086912079612f; // 1/sqrt(2048)

// ---------------------------------------------------------------------------
// Phase 1: pre = X @ W_in^T, written to out rows 1..SEQ (in-place scan buffer)
// ---------------------------------------------------------------------------
__global__ __launch_bounds__(256)
void gemm_pre_kernel(const float* __restrict__ A, const float* __restrict__ B,
                     float* __restrict__ out) {
    __shared__ float As[64][17];
    __shared__ float Bs[64][17];
    const int tid = threadIdx.x;
    const int tx = tid & 15, ty = tid >> 4;
    const int m0 = blockIdx.x * 64, n0 = blockIdx.y * 64;
    const int lr = tid >> 2;
    const int lk = (tid & 3) * 4;
    float acc[4][4] = {};
    for (int k0 = 0; k0 < IN; k0 += 16) {
        const float4 av = *(const float4*)&A[(size_t)(m0 + lr) * IN + k0 + lk];
        const float4 bv = *(const float4*)&B[(size_t)(n0 + lr) * IN + k0 + lk];
        __syncthreads();
        As[lr][lk + 0] = av.x; As[lr][lk + 1] = av.y;
        As[lr][lk + 2] = av.z; As[lr][lk + 3] = av.w;
        Bs[lr][lk + 0] = bv.x; Bs[lr][lk + 1] = bv.y;
        Bs[lr][lk + 2] = bv.z; Bs[lr][lk + 3] = bv.w;
        __syncthreads();
#pragma unroll
        for (int k = 0; k < 16; ++k) {
            float a[4], b[4];
#pragma unroll
            for (int i = 0; i < 4; ++i) a[i] = As[ty * 4 + i][k];
#pragma unroll
            for (int j = 0; j < 4; ++j) b[j] = Bs[tx * 4 + j][k];
#pragma unroll
            for (int i = 0; i < 4; ++i)
#pragma unroll
                for (int j = 0; j < 4; ++j) acc[i][j] += a[i] * b[j];
        }
    }
#pragma unroll
    for (int i = 0; i < 4; ++i) {
        float4 v = make_float4(acc[i][0], acc[i][1], acc[i][2], acc[i][3]);
        *(float4*)&out[(size_t)(m0 + ty * 4 + i + 1) * RS + n0 + tx * 4] = v;
    }
}

// fast tanh: 1 - 2/(exp(2x)+1); exact saturation at +/-inf, ~1e-7 rel err.
__device__ __forceinline__ float fast_tanh(float x) {
    float e = __expf(2.0f * x);
    return 1.0f - 2.0f * __builtin_amdgcn_rcpf(e + 1.0f);
}

typedef unsigned long long u64;
#define AT_LOAD_U64(p)     __hip_atomic_load((p), __ATOMIC_RELAXED, __HIP_MEMORY_SCOPE_AGENT)
#define AT_STORE_U32(p, v) __hip_atomic_store((p), (v), __ATOMIC_RELAXED, __HIP_MEMORY_SCOPE_AGENT)

// ---------------------------------------------------------------------------
// Phase 2: persistent scan, barrier-free dataflow with EPOCH-PARITY tags
// (R5 structure) + 4-deep software-pipelined polling.
// ring: RING rows x RS dwords in d_ws, memset-0 at call start (tag bit = 0).
// Epoch e lives in row e%8 with tag bit0 = ((e>>3)&1)^1; stale epoch e-8
// always carries the opposite tag; skew <= 1 rules out ABA at distance 16.
// No ring zeroing, no vmcnt drain: publish is a bare coalesced 128B sc1
// store after sync2.
// POLL: each thread keeps 4 outstanding loads on its u64 slot; checking the
// oldest compiles to s_waitcnt vmcnt(3), so readiness is sampled every
// ~latency/4 cycles instead of every full L3 round trip.
// ---------------------------------------------------------------------------
__global__ __launch_bounds__(BT, 1)
void reservoir_scan_kernel(const float* __restrict__ W_res,
                           const float* __restrict__ init,
                           float* __restrict__ out,
                           unsigned* __restrict__ ring32) {
    __shared__ float s_state[RS];
    __shared__ float s_pub[32];
    u64* ring = (u64*)ring32;
    const int bid  = blockIdx.x;
    const int tid  = threadIdx.x;
    const int wave = tid >> 6;
    const int lane = tid & 63;
    const int r0   = bid * 32 + wave * 2;

    // --- W rows r0, r0+1 into registers; pin against rematerialization ---
    const float* wp0 = W_res + (size_t)r0 * RS + lane * 4;
    const float* wp1 = wp0 + RS;
    float4 w0[8], w1[8];
#pragma unroll
    for (int j = 0; j < 8; ++j) {
        w0[j] = *(const float4*)(wp0 + j * 256);
        w1[j] = *(const float4*)(wp1 + j * 256);
    }
#pragma unroll
    for (int j = 0; j < 8; ++j) {
        asm volatile("" : "+v"(w0[j].x), "+v"(w0[j].y), "+v"(w0[j].z), "+v"(w0[j].w));
        asm volatile("" : "+v"(w1[j].x), "+v"(w1[j].y), "+v"(w1[j].z), "+v"(w1[j].w));
    }

    // --- epoch 0 (wrap 0, tag 1): out row 0 = init; publish; seed s_pub ---
    if (wave == 0 && lane < 32) {
        float v = init[bid * 32 + lane];
        out[bid * 32 + lane] = v;
        s_pub[lane] = v;
        AT_STORE_U32(ring32 + bid * 32 + lane, __float_as_uint(v) | 1u);
    }
    __syncthreads();

    for (int t = 0; t < SEQ; ++t) {
        const size_t crow = (size_t)(t & (RING - 1)) * (RS / 2);        // u64
        const size_t prow = (size_t)((t + 1) & (RING - 1)) * RS;        // u32
        const unsigned tag_c = ((unsigned)(t >> 3) & 1u) ^ 1u;          // consume
        const unsigned tag_p = ((unsigned)((t + 1) >> 3) & 1u) ^ 1u;    // publish

        // --- lane<2: preload pre early (overlaps the poll) ---
        float pre = 0.f;
        if (lane < 2) pre = out[(size_t)(t + 1) * RS + r0 + lane];

        // --- stage state row t into LDS ---
        if ((tid >> 4) == bid) {
            // own 128B slice: take decoded values from LDS, skip the L3 RT
            const int k = tid & 15;
            s_state[2 * tid]     = s_pub[2 * k];
            s_state[2 * tid + 1] = s_pub[2 * k + 1];
        } else {
            const u64* pp = ring + crow + tid;
            // 4-deep pipelined poll: oldest-check leaves 3 loads in flight.
            u64 v;
            u64 q0 = AT_LOAD_U64(pp);
            u64 q1 = AT_LOAD_U64(pp);
            u64 q2 = AT_LOAD_U64(pp);
            u64 q3 = AT_LOAD_U64(pp);
#define READY(x) (((((unsigned)(x) ^ tag_c) | ((unsigned)((x) >> 32) ^ tag_c)) & 1u) == 0u)
            for (;;) {
                if (READY(q0)) { v = q0; break; }
                q0 = AT_LOAD_U64(pp);
                if (READY(q1)) { v = q1; break; }
                q1 = AT_LOAD_U64(pp);
                if (READY(q2)) { v = q2; break; }
                q2 = AT_LOAD_U64(pp);
                if (READY(q3)) { v = q3; break; }
                q3 = AT_LOAD_U64(pp);
            }
#undef READY
            s_state[2 * tid]     = __uint_as_float((unsigned)v);
            s_state[2 * tid + 1] = __uint_as_float((unsigned)(v >> 32));
        }
        __syncthreads();

        // --- dot products: W regs x LDS state ---
        float a0 = 0.f, a1 = 0.f;
#pragma unroll
        for (int j = 0; j < 8; ++j) {
            const float4 sv = *(const float4*)&s_state[lane * 4 + j * 256];
            a0 += w0[j].x * sv.x + w0[j].y * sv.y + w0[j].z * sv.z + w0[j].w * sv.w;
            a1 += w1[j].x * sv.x + w1[j].y * sv.y + w1[j].z * sv.z + w1[j].w * sv.w;
        }
#pragma unroll
        for (int off = 32; off > 0; off >>= 1) {
            a0 += __shfl_xor(a0, off);
            a1 += __shfl_xor(a1, off);
        }

        // --- finish rows r0 (lane 0), r0+1 (lane 1); decoded -> s_pub ---
        if (lane < 2) {
            float a = lane ? a1 : a0;
            float s = fast_tanh(pre + a) * INV_SQRT;
            out[(size_t)(t + 1) * RS + r0 + lane] = s;   // plain store
            s_pub[wave * 2 + lane] = s;
        }
        __syncthreads();

        // --- publish: bare coalesced 128B sc1 store with parity tag ---
        if (wave == 0 && lane < 32) {
            unsigned bits = __float_as_uint(s_pub[lane]);
            AT_STORE_U32(ring32 + prow + bid * 32 + lane,
                         (bits & ~1u) | tag_p);
        }
    }
}

extern "C" void kernel_launch(void* const* d_in, const int* in_sizes, int n_in,
                              void* d_out, int out_size, void* d_ws, size_t ws_size,
                              hipStream_t stream) {
    const float* x     = (const float*)d_in[0];  // (4096, 512)
    const float* init  = (const float*)d_in[1];  // (2048,)
    const float* W_in  = (const float*)d_in[2];  // (2048, 512)
    const float* W_res = (const float*)d_in[3];  // (2048, 2048)
    float* out = (float*)d_out;                  // (4097, 2048)
    unsigned* ring = (unsigned*)d_ws;

    hipMemsetAsync(d_ws, 0, (size_t)RING * RS * sizeof(float), stream);
    gemm_pre_kernel<<<dim3(SEQ / 64, RS / 64), 256, 0, stream>>>(x, W_in, out);

    void* args[] = { (void*)&W_res, (void*)&init, (void*)&out, (void*)&ring };
    hipLaunchCooperativeKernel((void*)reservoir_scan_kernel,
                               dim3(GB), dim3(BT), args, 0, stream);
}

// Round 8
// 7792.898 us; speedup vs baseline: 1.1943x; 1.1943x over previous
//
#include <hip/hip_runtime.h>

constexpr int SEQ  = 4096;   // timesteps
constexpr int IN   = 512;    // input size
constexpr int RS   = 2048;   // reservoir size
constexpr int GB   = 64;     // blocks in scan kernel
constexpr int BT   = 512;    // threads per block in scan kernel (8 waves)
constexpr int RING = 8;      // ring depth (epochs); skew bound <= 1
constexpr float INV_SQRT = 0.022097086912079612f; // 1/sqrt(2048)

// ---------------------------------------------------------------------------
// Phase 1: pre = X @ W_in^T, written to out rows 1..SEQ (in-place scan buffer)
// ---------------------------------------------------------------------------
__global__ __launch_bounds__(256)
void gemm_pre_kernel(const float* __restrict__ A, const float* __restrict__ B,
                     float* __restrict__ out) {
    __shared__ float As[64][17];
    __shared__ float Bs[64][17];
    const int tid = threadIdx.x;
    const int tx = tid & 15, ty = tid >> 4;
    const int m0 = blockIdx.x * 64, n0 = blockIdx.y * 64;
    const int lr = tid >> 2;
    const int lk = (tid & 3) * 4;
    float acc[4][4] = {};
    for (int k0 = 0; k0 < IN; k0 += 16) {
        const float4 av = *(const float4*)&A[(size_t)(m0 + lr) * IN + k0 + lk];
        const float4 bv = *(const float4*)&B[(size_t)(n0 + lr) * IN + k0 + lk];
        __syncthreads();
        As[lr][lk + 0] = av.x; As[lr][lk + 1] = av.y;
        As[lr][lk + 2] = av.z; As[lr][lk + 3] = av.w;
        Bs[lr][lk + 0] = bv.x; Bs[lr][lk + 1] = bv.y;
        Bs[lr][lk + 2] = bv.z; Bs[lr][lk + 3] = bv.w;
        __syncthreads();
#pragma unroll
        for (int k = 0; k < 16; ++k) {
            float a[4], b[4];
#pragma unroll
            for (int i = 0; i < 4; ++i) a[i] = As[ty * 4 + i][k];
#pragma unroll
            for (int j = 0; j < 4; ++j) b[j] = Bs[tx * 4 + j][k];
#pragma unroll
            for (int i = 0; i < 4; ++i)
#pragma unroll
                for (int j = 0; j < 4; ++j) acc[i][j] += a[i] * b[j];
        }
    }
#pragma unroll
    for (int i = 0; i < 4; ++i) {
        float4 v = make_float4(acc[i][0], acc[i][1], acc[i][2], acc[i][3]);
        *(float4*)&out[(size_t)(m0 + ty * 4 + i + 1) * RS + n0 + tx * 4] = v;
    }
}

// fast tanh: 1 - 2/(exp(2x)+1); exact saturation at +/-inf, ~1e-7 rel err.
__device__ __forceinline__ float fast_tanh(float x) {
    float e = __expf(2.0f * x);
    return 1.0f - 2.0f * __builtin_amdgcn_rcpf(e + 1.0f);
}

typedef unsigned long long u64;
#define AT_LOAD_U64(p)     __hip_atomic_load((p), __ATOMIC_RELAXED, __HIP_MEMORY_SCOPE_AGENT)
#define AT_STORE_U32(p, v) __hip_atomic_store((p), (v), __ATOMIC_RELAXED, __HIP_MEMORY_SCOPE_AGENT)

// ---------------------------------------------------------------------------
// Phase 2: persistent scan, barrier-free dataflow with EPOCH-PARITY tags
// (R5 protocol), restructured compute: 8 waves x 4 rows/wave.
//  - Each wave reads the 8KB state from LDS ONCE for 4 rows (halves LDS
//    ds_read traffic vs 16 waves x 2 rows).
//  - Multi-value butterfly: 4 accumulators reduced in 7 shfls total
//    (2 select-exchange levels -> row = lane&3, then 4 xor levels).
// ring: RING rows x RS dwords in d_ws, memset-0 at call start (tag bit 0).
// Epoch e lives in row e%8 with tag bit0 = ((e>>3)&1)^1; stale epoch e-8
// carries the opposite tag; skew <= 1 rules out ABA at distance 16.
// No zeroing, no vmcnt drain: publish = bare coalesced 128B sc1 store.
// Block b owns rows [b*32, b*32+32); wave w rows b*32 + 4w + {0..3}.
// Thread tid polls u64 slots {2tid, 2tid+1} (4 floats); the 8 threads whose
// floats fall in the block's own 128B slice read s_pub from LDS instead.
// ---------------------------------------------------------------------------
__global__ __launch_bounds__(BT, 2)
void reservoir_scan_kernel(const float* __restrict__ W_res,
                           const float* __restrict__ init,
                           float* __restrict__ out,
                           unsigned* __restrict__ ring32) {
    __shared__ float s_state[RS];
    __shared__ float s_pub[32];
    u64* ring = (u64*)ring32;
    const int bid  = blockIdx.x;
    const int tid  = threadIdx.x;
    const int wave = tid >> 6;
    const int lane = tid & 63;
    const int r0   = bid * 32 + wave * 4;     // first of this wave's 4 rows

    // --- W rows r0..r0+3 into registers (4 x 8 float4 = 128 VGPR); pin ---
    float4 w[4][8];
#pragma unroll
    for (int r = 0; r < 4; ++r) {
        const float* wp = W_res + (size_t)(r0 + r) * RS + lane * 4;
#pragma unroll
        for (int j = 0; j < 8; ++j) w[r][j] = *(const float4*)(wp + j * 256);
    }
#pragma unroll
    for (int r = 0; r < 4; ++r)
#pragma unroll
        for (int j = 0; j < 8; ++j)
            asm volatile("" : "+v"(w[r][j].x), "+v"(w[r][j].y),
                              "+v"(w[r][j].z), "+v"(w[r][j].w));

    // --- epoch 0 (wrap 0, tag 1): out row 0 = init; publish; seed s_pub ---
    if (wave == 0 && lane < 32) {
        float v = init[bid * 32 + lane];
        out[bid * 32 + lane] = v;
        s_pub[lane] = v;
        AT_STORE_U32(ring32 + bid * 32 + lane, __float_as_uint(v) | 1u);
    }
    __syncthreads();

    for (int t = 0; t < SEQ; ++t) {
        const size_t crow = (size_t)(t & (RING - 1)) * (RS / 2);        // u64
        const size_t prow = (size_t)((t + 1) & (RING - 1)) * RS;        // u32
        const unsigned tag_c = ((unsigned)(t >> 3) & 1u) ^ 1u;          // consume
        const unsigned tag_p = ((unsigned)((t + 1) >> 3) & 1u) ^ 1u;    // publish

        // --- lane<4: preload pre early (overlaps the poll) ---
        float pre = 0.f;
        if (lane < 4) pre = out[(size_t)(t + 1) * RS + r0 + lane];

        // --- stage state row t into LDS: thread tid -> floats [4tid,4tid+4) ---
        if ((tid >> 3) == bid) {
            const int k = tid & 7;
            *(float4*)&s_state[4 * tid] = *(const float4*)&s_pub[4 * k];
        } else {
            const u64* pp = ring + crow + 2 * tid;
            u64 v0 = AT_LOAD_U64(pp);
            u64 v1 = AT_LOAD_U64(pp + 1);
#define RDY(x) (((((unsigned)(x) ^ tag_c) | ((unsigned)((x) >> 32) ^ tag_c)) & 1u) == 0u)
            while (!(RDY(v0) && RDY(v1))) {
                v0 = AT_LOAD_U64(pp);
                v1 = AT_LOAD_U64(pp + 1);
            }
#undef RDY
            float4 sv;
            sv.x = __uint_as_float((unsigned)v0);
            sv.y = __uint_as_float((unsigned)(v0 >> 32));
            sv.z = __uint_as_float((unsigned)v1);
            sv.w = __uint_as_float((unsigned)(v1 >> 32));
            *(float4*)&s_state[4 * tid] = sv;
        }
        __syncthreads();

        // --- 4-row dot: W regs x LDS state (one 8KB pass per wave) ---
        float a0 = 0.f, a1 = 0.f, a2 = 0.f, a3 = 0.f;
#pragma unroll
        for (int j = 0; j < 8; ++j) {
            const float4 sv = *(const float4*)&s_state[lane * 4 + j * 256];
            a0 += w[0][j].x * sv.x + w[0][j].y * sv.y + w[0][j].z * sv.z + w[0][j].w * sv.w;
            a1 += w[1][j].x * sv.x + w[1][j].y * sv.y + w[1][j].z * sv.z + w[1][j].w * sv.w;
            a2 += w[2][j].x * sv.x + w[2][j].y * sv.y + w[2][j].z * sv.z + w[2][j].w * sv.w;
            a3 += w[3][j].x * sv.x + w[3][j].y * sv.y + w[3][j].z * sv.z + w[3][j].w * sv.w;
        }

        // --- multi-value butterfly: 7 shfls; lane l ends with row (l&3) ---
        const bool p1 = (lane & 1) != 0;
        float k01 = p1 ? a1 : a0, s01 = p1 ? a0 : a1;
        k01 += __shfl_xor(s01, 1);
        float k23 = p1 ? a3 : a2, s23 = p1 ? a2 : a3;
        k23 += __shfl_xor(s23, 1);
        const bool p2 = (lane & 2) != 0;
        float kk = p2 ? k23 : k01, ss = p2 ? k01 : k23;
        kk += __shfl_xor(ss, 2);
        kk += __shfl_xor(kk, 4);
        kk += __shfl_xor(kk, 8);
        kk += __shfl_xor(kk, 16);
        kk += __shfl_xor(kk, 32);

        // --- lane<4: finish row r0+lane; plain out store; decoded->s_pub ---
        if (lane < 4) {
            float s = fast_tanh(pre + kk) * INV_SQRT;
            out[(size_t)(t + 1) * RS + r0 + lane] = s;
            s_pub[wave * 4 + lane] = s;
        }
        __syncthreads();

        // --- publish: bare coalesced 128B sc1 store with parity tag ---
        if (wave == 0 && lane < 32) {
            unsigned bits = __float_as_uint(s_pub[lane]);
            AT_STORE_U32(ring32 + prow + bid * 32 + lane,
                         (bits & ~1u) | tag_p);
        }
    }
}

extern "C" void kernel_launch(void* const* d_in, const int* in_sizes, int n_in,
                              void* d_out, int out_size, void* d_ws, size_t ws_size,
                              hipStream_t stream) {
    const float* x     = (const float*)d_in[0];  // (4096, 512)
    const float* init  = (const float*)d_in[1];  // (2048,)
    const float* W_in  = (const float*)d_in[2];  // (2048, 512)
    const float* W_res = (const float*)d_in[3];  // (2048, 2048)
    float* out = (float*)d_out;                  // (4097, 2048)
    unsigned* ring = (unsigned*)d_ws;

    hipMemsetAsync(d_ws, 0, (size_t)RING * RS * sizeof(float), stream);
    gemm_pre_kernel<<<dim3(SEQ / 64, RS / 64), 256, 0, stream>>>(x, W_in, out);

    void* args[] = { (void*)&W_res, (void*)&init, (void*)&out, (void*)&ring };
    hipLaunchCooperativeKernel((void*)reservoir_scan_kernel,
                               dim3(GB), dim3(BT), args, 0, stream);
}